// Round 6
// baseline (1710.554 us; speedup 1.0000x reference)
//
#include <hip/hip_runtime.h>
#include <cmath>

// B=8, Cin=16, H=W=128, Cout=64, E=16, K=2
typedef __attribute__((ext_vector_type(8))) short bf16x8;   // MFMA A/B frag
typedef __attribute__((ext_vector_type(4))) float f32x4;    // MFMA C/D frag

#define LIST_CAP 32768                      // per-expert entry cap (mean ~16384)
// ws layout (bytes):
#define WS_GCNT 0                           // int[16]
#define WS_LIST 64                          // int2[16][LIST_CAP] = 4,194,304
#define WS_WB   (64 + 16 * LIST_CAP * 8)    // 4,194,368: bf16[1024][160] = 327,680
#define WS_AG   (WS_WB + 327680)            // 4,522,048: bf16[131072][160] = 41,943,040
#define WS_END  (WS_AG + 131072 * 160 * 2)  // ~46.5 MB total

static __device__ __forceinline__ unsigned int f2bf(float f) {
    union { float f; unsigned int u; } v; v.f = f;
    unsigned int r = v.u + 0x7FFFu + ((v.u >> 16) & 1u);   // round-to-nearest-even
    return r >> 16;
}

// ---- K1: gate + logits + routing scatter + global im2col (bf16) + weight convert ----
__global__ __launch_bounds__(256) void k1_route(
    const float* __restrict__ x,       // [8][16][128][128]
    const float* __restrict__ gw,      // [16][16]
    const float* __restrict__ gb,      // [16]
    const float* __restrict__ ew,      // [16][64][144]
    float* __restrict__ logits_out,    // [8][16][128][128]
    int* __restrict__ gcnt,            // [16]
    int2* __restrict__ list,           // [16][LIST_CAP] (pix, w-bits)
    unsigned short* __restrict__ wb,   // [1024][160] bf16
    unsigned short* __restrict__ ag)   // [131072][160] bf16 im2col rows
{
    __shared__ float xt[8448];         // [16 ci][4 r][132 c], rows r0-1..r0+2, cols -1..130
    const int tid = threadIdx.x;
    const int blk = blockIdx.x;        // 512 blocks: 2 rows each
    const int b   = blk >> 6;
    const int r0  = (blk & 63) << 1;

    for (int i = tid; i < 8448; i += 256) {
        int ci  = i / 528;
        int rem = i - ci * 528;
        int r   = rem / 132;
        int cc  = rem - r * 132;
        int gr = r0 - 1 + r, gc = cc - 1;
        float v = 0.f;
        if (gr >= 0 && gr < 128 && gc >= 0 && gc < 128)
            v = x[((b * 16 + ci) * 128 + gr) * 128 + gc];
        xt[i] = v;
    }

    // weight convert: 512 blocks x 40 chunks = 20480 chunks (18 data + 2 zero pad per row)
    if (tid < 40) {
        const int chunk = blk * 40 + tid;
        const int rowid = chunk / 20;
        const int kc    = chunk - rowid * 20;
        uint4 dv = make_uint4(0u, 0u, 0u, 0u);
        if (kc < 18) {
            const float4 a = *(const float4*)(ew + rowid * 144 + kc * 8);
            const float4 c = *(const float4*)(ew + rowid * 144 + kc * 8 + 4);
            dv.x = f2bf(a.x) | (f2bf(a.y) << 16);
            dv.y = f2bf(a.z) | (f2bf(a.w) << 16);
            dv.z = f2bf(c.x) | (f2bf(c.y) << 16);
            dv.w = f2bf(c.z) | (f2bf(c.w) << 16);
        }
        *(uint4*)(wb + rowid * 160 + kc * 8) = dv;
    }
    __syncthreads();

    // gate (fp32, exact) — one thread per pixel
    const int col  = tid & 127;
    const int prow = tid >> 7;
    float xv[16];
    #pragma unroll
    for (int ci = 0; ci < 16; ++ci) xv[ci] = xt[ci * 528 + (prow + 1) * 132 + col + 1];
    float l[16];
    #pragma unroll
    for (int o = 0; o < 16; ++o) {
        float acc = gb[o];
        #pragma unroll
        for (int i = 0; i < 16; ++i) acc += gw[o * 16 + i] * xv[i];
        l[o] = acc;
    }
    const int rbase = ((b * 16) * 128 + (r0 + prow)) * 128 + col;
    #pragma unroll
    for (int o = 0; o < 16; ++o) logits_out[rbase + o * 16384] = l[o];

    float m = l[0];
    #pragma unroll
    for (int o = 1; o < 16; ++o) m = fmaxf(m, l[o]);
    float p0 = expf(l[0] - m), p1 = -1.f;
    int i0 = 0, i1 = 0;
    #pragma unroll
    for (int o = 1; o < 16; ++o) {
        float pv = expf(l[o] - m);
        if (pv > p0)      { p1 = p0; i1 = i0; p0 = pv; i0 = o; }
        else if (pv > p1) { p1 = pv; i1 = o; }
    }
    const float ws = p0 + p1;
    const float w0 = p0 / ws, w1 = p1 / ws;

    const int pix = b * 16384 + (r0 + prow) * 128 + col;
    {
        int p = atomicAdd(&gcnt[i0], 1);
        if (p < LIST_CAP) list[i0 * LIST_CAP + p] = make_int2(pix, __float_as_int(w0));
        p = atomicAdd(&gcnt[i1], 1);
        if (p < LIST_CAP) list[i1 * LIST_CAP + p] = make_int2(pix, __float_as_int(w1));
    }

    // im2col row for this pixel: 160 bf16 (144 data + 16 zero), 20 x 16B chunks
    unsigned short* arow = ag + pix * 160;
    #pragma unroll
    for (int c = 0; c < 18; ++c) {
        unsigned int d[4];
        #pragma unroll
        for (int h = 0; h < 4; ++h) {
            unsigned int lo, hi;
            {
                const int k = c * 8 + h * 2;
                const int ci = k / 9, rr = k - ci * 9, ky = rr / 3, kx = rr - ky * 3;
                lo = f2bf(xt[ci * 528 + (prow + ky) * 132 + col + kx]);
            }
            {
                const int k = c * 8 + h * 2 + 1;
                const int ci = k / 9, rr = k - ci * 9, ky = rr / 3, kx = rr - ky * 3;
                hi = f2bf(xt[ci * 528 + (prow + ky) * 132 + col + kx]);
            }
            d[h] = lo | (hi << 16);
        }
        *(uint4*)(arow + c * 8) = make_uint4(d[0], d[1], d[2], d[3]);
    }
    *(uint4*)(arow + 144) = make_uint4(0u, 0u, 0u, 0u);
    *(uint4*)(arow + 152) = make_uint4(0u, 0u, 0u, 0u);
}

// ---- K2: grouped implicit GEMM, one expert per block-tile of 256 entries ----
__global__ __launch_bounds__(512) void k2_gemm(
    const int* __restrict__ gcnt,
    const int2* __restrict__ list,
    const unsigned short* __restrict__ wb,
    const unsigned short* __restrict__ ag,
    const float* __restrict__ eb,      // [16][64]
    float* __restrict__ out)           // [8][64][128][128], pre-zeroed
{
    __shared__ int   lpix[256];
    __shared__ float lw[256];
    const int e  = blockIdx.x >> 7;     // 16 experts x 128 tiles
    const int ti = blockIdx.x & 127;
    int cnt = gcnt[e]; cnt = cnt < LIST_CAP ? cnt : LIST_CAP;
    const int n0 = ti << 8;
    if (n0 >= cnt) return;
    const int nn = (cnt - n0) < 256 ? (cnt - n0) : 256;
    const int tid = threadIdx.x;
    if (tid < 256) {
        const int idx = n0 + (tid < nn ? tid : nn - 1);   // clamp pad rows (masked later)
        const int2 v = list[e * LIST_CAP + idx];
        lpix[tid] = v.x;
        lw[tid]   = (tid < nn) ? __int_as_float(v.y) : 0.f;
    }
    __syncthreads();

    const int lane = tid & 63, wave = tid >> 6;
    const int quad = lane >> 4, lq = lane & 15;
    const int nf   = wave & 3;          // n-fragment (16 couts)
    const int mh   = wave >> 2;         // m-tile phase (2 waves per nf)
    const int n    = lq + 16 * nf;

    // B frags hoisted once per tile per wave (bf16, from L2-hot wb)
    const unsigned short* brow = wb + (e * 64 + n) * 160 + quad * 8;
    bf16x8 bfr[5];
    #pragma unroll
    for (int ks = 0; ks < 5; ++ks) bfr[ks] = *(const bf16x8*)(brow + ks * 32);
    const float bias = eb[e * 64 + n];

    const int mtiles = (nn + 15) >> 4;
    #pragma unroll 2
    for (int mt = mh; mt < mtiles; mt += 2) {
        const int mbase = mt << 4;
        const unsigned short* arow = ag + lpix[mbase + lq] * 160 + quad * 8;
        bf16x8 av[5];
        #pragma unroll
        for (int ks = 0; ks < 5; ++ks) av[ks] = *(const bf16x8*)(arow + ks * 32);
        f32x4 acc = {0.f, 0.f, 0.f, 0.f};
        #pragma unroll
        for (int ks = 0; ks < 5; ++ks)
            acc = __builtin_amdgcn_mfma_f32_16x16x32_bf16(av[ks], bfr[ks], acc, 0, 0, 0);
        #pragma unroll
        for (int r = 0; r < 4; ++r) {       // C/D row = quad*4 + r
            const int mm = mbase + quad * 4 + r;
            if (mm < nn) {
                const int   p = lpix[mm];
                const float w = lw[mm];
                // out[(b*64+n)][row][col]; b = p>>14, row*128+col = p&16383
                atomicAdd(out + ((p >> 14) * 64 + n) * 16384 + (p & 16383),
                          w * (acc[r] + bias));
            }
        }
    }
}

extern "C" void kernel_launch(void* const* d_in, const int* in_sizes, int n_in,
                              void* d_out, int out_size, void* d_ws, size_t ws_size,
                              hipStream_t stream) {
    const float* x  = (const float*)d_in[0];
    const float* gw = (const float*)d_in[1];
    const float* gb = (const float*)d_in[2];
    const float* ew = (const float*)d_in[3];
    const float* eb = (const float*)d_in[4];
    float* out        = (float*)d_out;
    float* logits_out = out + 8 * 64 * 128 * 128;

    char* ws = (char*)d_ws;
    int*            gcnt = (int*)(ws + WS_GCNT);
    int2*           list = (int2*)(ws + WS_LIST);
    unsigned short* wb   = (unsigned short*)(ws + WS_WB);
    unsigned short* ag   = (unsigned short*)(ws + WS_AG);

    hipMemsetAsync(gcnt, 0, 64, stream);
    hipMemsetAsync(out, 0, (size_t)8 * 64 * 128 * 128 * sizeof(float), stream);
    k1_route<<<dim3(512), dim3(256), 0, stream>>>(x, gw, gb, ew, logits_out,
                                                  gcnt, list, wb, ag);
    k2_gemm<<<dim3(2048), dim3(512), 0, stream>>>(gcnt, list, wb, ag, eb, out);
}

// Round 7
// 130.555 us; speedup vs baseline: 13.1022x; 13.1022x over previous
//
#include <hip/hip_runtime.h>
#include <cmath>

// B=8, Cin=16, H=W=128, Cout=64, E=16, K=2
typedef __attribute__((ext_vector_type(8))) short bf16x8;   // MFMA A/B frag
typedef __attribute__((ext_vector_type(4))) float f32x4;    // MFMA C/D frag

static __device__ __forceinline__ unsigned int f2bf(float f) {
    union { float f; unsigned int u; } v; v.f = f;
    unsigned int r = v.u + 0x7FFFu + ((v.u >> 16) & 1u);   // round-to-nearest-even
    return r >> 16;
}

// ---- prep: ew [16][64][144] fp32 -> wb [e*64+cout][160] bf16 (B-frag rows, k-pad zeroed) ----
__global__ __launch_bounds__(256) void prep_w_kernel(const float* __restrict__ ew,
                                                     unsigned short* __restrict__ wb) {
    const int chunk = blockIdx.x * 256 + threadIdx.x;   // one 8-bf16 chunk
    if (chunk >= 20480) return;                         // 1024 rows * 20 chunks
    const int rowid = chunk / 20;
    const int kc    = chunk - rowid * 20;
    uint4 dv = make_uint4(0u, 0u, 0u, 0u);
    if (kc < 18) {                                      // chunks 18,19 = zero k-pad
        const float4 a = *(const float4*)(ew + rowid * 144 + kc * 8);
        const float4 c = *(const float4*)(ew + rowid * 144 + kc * 8 + 4);
        dv.x = f2bf(a.x) | (f2bf(a.y) << 16);
        dv.y = f2bf(a.z) | (f2bf(a.w) << 16);
        dv.z = f2bf(c.x) | (f2bf(c.y) << 16);
        dv.w = f2bf(c.z) | (f2bf(c.w) << 16);
    }
    *(uint4*)(wb + rowid * 160 + kc * 8) = dv;
}

// ---- main: dense per-expert GEMM, gate-weighted accumulation, zero atomics ----
// grid: 2048 = b(8) x row(128) x half(2); block: 256 thr = 4 waves (wave = n-frag)
__global__ __launch_bounds__(256, 3) void moe_dense_kernel(
    const float* __restrict__ x,              // [8][16][128][128]
    const float* __restrict__ gw,             // [16][16]
    const float* __restrict__ gb,             // [16]
    const unsigned short* __restrict__ wb,    // [1024][160] bf16
    const float* __restrict__ eb,             // [16][64]
    float* __restrict__ out,                  // [8][64][128][128]
    float* __restrict__ logits_out)           // [8][16][128][128]
{
    __shared__ __align__(16) unsigned short Ab[64 * 160];   // im2col bf16 [px][160]
    __shared__ __align__(16) float wexp[16 * 64];           // [e][px] gate weight (0 if unrouted)
    __shared__ float outt[64 * 65];                         // transpose bounce

    const int tid = threadIdx.x;
    const int b   = blockIdx.x >> 8;
    const int row = (blockIdx.x >> 1) & 127;
    const int px0 = (blockIdx.x & 1) << 6;

    const int lane = tid & 63;
    const int wave = tid >> 6;           // 0..3 = n-frag
    const int quad = lane >> 4;
    const int lq   = lane & 15;
    const int n    = lq + 16 * wave;     // this lane's cout

    // ---- zero wexp ----
    for (int i = tid; i < 1024; i += 256) wexp[i] = 0.f;
    __syncthreads();

    // ---- gate (fp32, exact): threads 0..63, one per pixel ----
    if (tid < 64) {
        const int col = px0 + tid;
        const float* xp = x + (b * 16) * 16384 + row * 128 + col;
        float xv[16];
        #pragma unroll
        for (int ci = 0; ci < 16; ++ci) xv[ci] = xp[ci * 16384];
        float l[16];
        #pragma unroll
        for (int o = 0; o < 16; ++o) {
            float acc = gb[o];
            #pragma unroll
            for (int i = 0; i < 16; ++i) acc += gw[o * 16 + i] * xv[i];
            l[o] = acc;
        }
        const int rbase = ((b * 16) * 128 + row) * 128 + col;
        #pragma unroll
        for (int o = 0; o < 16; ++o) logits_out[rbase + o * 16384] = l[o];

        float m = l[0];
        #pragma unroll
        for (int o = 1; o < 16; ++o) m = fmaxf(m, l[o]);
        float p0 = expf(l[0] - m), p1 = -1.f;
        int i0 = 0, i1 = 0;
        #pragma unroll
        for (int o = 1; o < 16; ++o) {
            float pv = expf(l[o] - m);
            if (pv > p0)      { p1 = p0; i1 = i0; p0 = pv; i0 = o; }
            else if (pv > p1) { p1 = pv; i1 = o; }
        }
        const float ws = p0 + p1;
        wexp[i0 * 64 + tid] = p0 / ws;   // each px column written only by its own thread
        wexp[i1 * 64 + tid] = p1 / ws;
    }

    // ---- im2col A build (all 256 threads; batched loads then convert) ----
    {
        const int px  = tid & 63;
        const int s0  = tid >> 6;        // 0..3
        const int col = px0 + px;
        float xa[36];
        #pragma unroll
        for (int j = 0; j < 12; ++j) {
            const int s  = s0 + 4 * j;
            const int ci = s / 3;
            const int ky = s - ci * 3;
            int gr = row - 1 + ky;
            gr = gr < 0 ? 0 : (gr > 127 ? 127 : gr);
            const float* xr = x + ((b * 16 + ci) * 128 + gr) * 128;
            xa[3 * j + 0] = (col > 0)   ? xr[col - 1] : 0.f;
            xa[3 * j + 1] = xr[col];
            xa[3 * j + 2] = (col < 127) ? xr[col + 1] : 0.f;
        }
        #pragma unroll
        for (int j = 0; j < 12; ++j) {
            const int s  = s0 + 4 * j;
            const int ci = s / 3;
            const int ky = s - ci * 3;
            const int gr = row - 1 + ky;
            const bool ok = (gr >= 0) && (gr < 128);
            unsigned short* dst = Ab + px * 160 + ci * 9 + ky * 3;
            dst[0] = ok ? (unsigned short)f2bf(xa[3 * j + 0]) : (unsigned short)0;
            dst[1] = ok ? (unsigned short)f2bf(xa[3 * j + 1]) : (unsigned short)0;
            dst[2] = ok ? (unsigned short)f2bf(xa[3 * j + 2]) : (unsigned short)0;
        }
    }
    if (tid < 128) {                     // zero A k-pad 144..159 (2 x uint4 per row)
        const int px = tid >> 1, h = tid & 1;
        *(uint4*)(Ab + px * 160 + 144 + h * 8) = make_uint4(0u, 0u, 0u, 0u);
    }
    __syncthreads();

    // ---- hoist A into registers: af[mt][ks], rows mt*16+lq, k-chunk quad*8+ks*32 ----
    bf16x8 af[4][5];
    #pragma unroll
    for (int mt = 0; mt < 4; ++mt) {
        const unsigned short* arow = Ab + (mt * 16 + lq) * 160 + quad * 8;
        #pragma unroll
        for (int ks = 0; ks < 5; ++ks) af[mt][ks] = *(const bf16x8*)(arow + ks * 32);
    }

    // ---- dense e-loop: B register-prefetched from L2-hot wb, weighted reg accumulation ----
    const unsigned short* bp = wb + n * 160 + quad * 8;   // + e*10240 per expert
    bf16x8 bn[5];
    #pragma unroll
    for (int ks = 0; ks < 5; ++ks) bn[ks] = *(const bf16x8*)(bp + ks * 32);
    float bnb = eb[n];

    f32x4 facc[4] = {{0.f,0.f,0.f,0.f},{0.f,0.f,0.f,0.f},{0.f,0.f,0.f,0.f},{0.f,0.f,0.f,0.f}};

    for (int e = 0; e < 16; ++e) {
        bf16x8 bc[5];
        #pragma unroll
        for (int ks = 0; ks < 5; ++ks) bc[ks] = bn[ks];
        const float bias = bnb;
        if (e < 15) {                    // prefetch next expert
            const unsigned short* p = bp + (e + 1) * 10240;
            #pragma unroll
            for (int ks = 0; ks < 5; ++ks) bn[ks] = *(const bf16x8*)(p + ks * 32);
            bnb = eb[(e + 1) * 64 + n];
        }
        #pragma unroll
        for (int mt = 0; mt < 4; ++mt) {
            const f32x4 wv = *(const f32x4*)&wexp[e * 64 + mt * 16 + quad * 4];  // broadcast in quad
            f32x4 acc = {0.f, 0.f, 0.f, 0.f};
            #pragma unroll
            for (int ks = 0; ks < 5; ++ks)
                acc = __builtin_amdgcn_mfma_f32_16x16x32_bf16(af[mt][ks], bc[ks], acc, 0, 0, 0);
            #pragma unroll
            for (int r = 0; r < 4; ++r)                 // C/D: row=quad*4+r, col=lq
                facc[mt][r] += wv[r] * (acc[r] + bias); // wv=0 for unrouted -> exact 0
        }
    }

    // ---- transpose bounce + coalesced writeout ----
    #pragma unroll
    for (int mt = 0; mt < 4; ++mt)
        #pragma unroll
        for (int r = 0; r < 4; ++r)
            outt[(mt * 16 + quad * 4 + r) * 65 + n] = facc[mt][r];
    __syncthreads();
    for (int i = tid; i < 4096; i += 256) {
        const int c = i >> 6, px = i & 63;
        out[((b * 64 + c) * 128 + row) * 128 + px0 + px] = outt[px * 65 + c];
    }
}

extern "C" void kernel_launch(void* const* d_in, const int* in_sizes, int n_in,
                              void* d_out, int out_size, void* d_ws, size_t ws_size,
                              hipStream_t stream) {
    const float* x  = (const float*)d_in[0];
    const float* gw = (const float*)d_in[1];
    const float* gb = (const float*)d_in[2];
    const float* ew = (const float*)d_in[3];
    const float* eb = (const float*)d_in[4];
    float* out        = (float*)d_out;
    float* logits_out = out + 8 * 64 * 128 * 128;
    unsigned short* wb = (unsigned short*)d_ws;      // 1024*160*2 = 327,680 B

    prep_w_kernel<<<dim3(80), dim3(256), 0, stream>>>(ew, wb);
    moe_dense_kernel<<<dim3(2048), dim3(256), 0, stream>>>(
        x, gw, gb, wb, eb, out, logits_out);
}